// Round 1
// baseline (53.497 us; speedup 1.0000x reference)
//
#include <hip/hip_runtime.h>

#define FS   5
#define NTAP 25
#define Bc   8
#define Cc   32
#define Hc   128
#define Wc   128
#define HW   (Hc * Wc)

#define TH     8          // rows per tile in apply kernel
#define Gc     8          // channels per block in apply kernel
#define HALO_H (TH + 4)   // 12
#define HALO_W (Wc + 4)   // 132

// ---------------- Kernel 1: per-pixel filter generation ----------------
// filt[b][t][h][w] = sum_c wg[t][c] * x[b][c][h][w] + bg[t]
__global__ __launch_bounds__(256) void gen_filters_kernel(
    const float* __restrict__ x, const float* __restrict__ wg,
    const float* __restrict__ bg, float* __restrict__ filt)
{
    const int p = blockIdx.x * 256 + threadIdx.x;   // pixel index within image
    const int b = blockIdx.y;

    const float* xb = x + (size_t)b * Cc * HW + p;
    float xv[Cc];
#pragma unroll
    for (int c = 0; c < Cc; ++c) xv[c] = xb[(size_t)c * HW];

    float f[NTAP];
#pragma unroll
    for (int t = 0; t < NTAP; ++t) f[t] = bg[t];

#pragma unroll
    for (int t = 0; t < NTAP; ++t) {
#pragma unroll
        for (int c = 0; c < Cc; ++c) {
            f[t] = fmaf(wg[t * Cc + c], xv[c], f[t]);
        }
    }

    float* fb = filt + (size_t)b * NTAP * HW + p;
#pragma unroll
    for (int t = 0; t < NTAP; ++t) fb[(size_t)t * HW] = f[t];
}

// ---------------- Kernel 2: apply dynamic filters (5x5 stencil) ----------------
// Each thread: 4 consecutive outputs along w (float4), filters in registers,
// loops over Gc channels with halo tile staged in LDS.
template <bool GEN_INLINE>
__global__ __launch_bounds__(256, 2) void apply_filters_kernel(
    const float* __restrict__ x, const float* __restrict__ filt,
    const float* __restrict__ wg, const float* __restrict__ bg,
    float* __restrict__ out)
{
    __shared__ float xs[HALO_H][HALO_W];

    const int tx = threadIdx.x;        // 0..31
    const int ty = threadIdx.y;        // 0..7
    const int h0 = blockIdx.x * TH;
    const int cg = blockIdx.y;         // channel group
    const int b  = blockIdx.z;
    const int h  = h0 + ty;
    const int w4 = tx * 4;

    float4 f[NTAP];
    if (GEN_INLINE) {
        // recompute the 25 filter values for this thread's 4 pixels
#pragma unroll
        for (int t = 0; t < NTAP; ++t) {
            float bv = bg[t];
            f[t] = make_float4(bv, bv, bv, bv);
        }
        const float* xpix = x + (size_t)b * Cc * HW + h * Wc + w4;
#pragma unroll
        for (int c = 0; c < Cc; ++c) {
            float4 xv = *reinterpret_cast<const float4*>(xpix + (size_t)c * HW);
#pragma unroll
            for (int t = 0; t < NTAP; ++t) {
                float wv = wg[t * Cc + c];
                f[t].x = fmaf(wv, xv.x, f[t].x);
                f[t].y = fmaf(wv, xv.y, f[t].y);
                f[t].z = fmaf(wv, xv.z, f[t].z);
                f[t].w = fmaf(wv, xv.w, f[t].w);
            }
        }
    } else {
        const float* fb = filt + (size_t)b * NTAP * HW + h * Wc + w4;
#pragma unroll
        for (int t = 0; t < NTAP; ++t)
            f[t] = *reinterpret_cast<const float4*>(fb + (size_t)t * HW);
    }

    const int tid = ty * 32 + tx;                      // 0..255
    const float* xb = x   + ((size_t)b * Cc + cg * Gc) * HW;
    float*       ob = out + ((size_t)b * Cc + cg * Gc) * HW;

    for (int g = 0; g < Gc; ++g) {
        __syncthreads();   // protect xs from previous iteration's readers
        // ---- stage halo tile for channel (cg*Gc + g) ----
        const float* xc = xb + (size_t)g * HW;
        for (int i = tid; i < HALO_H * HALO_W; i += 256) {
            const int r  = i / HALO_W;
            const int cw = i - r * HALO_W;
            const int gh = h0 - 2 + r;
            const int gw = cw - 2;
            float v = 0.0f;
            if ((unsigned)gh < (unsigned)Hc && (unsigned)gw < (unsigned)Wc)
                v = xc[gh * Wc + gw];
            xs[r][cw] = v;
        }
        __syncthreads();

        // ---- 5x5 stencil, 4 outputs per thread ----
        float4 acc = make_float4(0.f, 0.f, 0.f, 0.f);
#pragma unroll
        for (int di = 0; di < FS; ++di) {
            float w8[8];
#pragma unroll
            for (int k = 0; k < 8; ++k) w8[k] = xs[ty + di][w4 + k];
#pragma unroll
            for (int dj = 0; dj < FS; ++dj) {
                const float4 ft = f[di * FS + dj];
                acc.x = fmaf(ft.x, w8[0 + dj], acc.x);
                acc.y = fmaf(ft.y, w8[1 + dj], acc.y);
                acc.z = fmaf(ft.z, w8[2 + dj], acc.z);
                acc.w = fmaf(ft.w, w8[3 + dj], acc.w);
            }
        }
        *reinterpret_cast<float4*>(ob + (size_t)g * HW + h * Wc + w4) = acc;
    }
}

extern "C" void kernel_launch(void* const* d_in, const int* in_sizes, int n_in,
                              void* d_out, int out_size, void* d_ws, size_t ws_size,
                              hipStream_t stream) {
    const float* x  = (const float*)d_in[0];
    const float* wg = (const float*)d_in[1];
    const float* bg = (const float*)d_in[2];
    float* out = (float*)d_out;

    const size_t filt_bytes = (size_t)Bc * NTAP * HW * sizeof(float);

    if (ws_size >= filt_bytes) {
        float* filt = (float*)d_ws;
        gen_filters_kernel<<<dim3(HW / 256, Bc), 256, 0, stream>>>(x, wg, bg, filt);
        apply_filters_kernel<false><<<dim3(Hc / TH, Cc / Gc, Bc), dim3(32, 8), 0, stream>>>(
            x, filt, wg, bg, out);
    } else {
        apply_filters_kernel<true><<<dim3(Hc / TH, Cc / Gc, Bc), dim3(32, 8), 0, stream>>>(
            x, nullptr, wg, bg, out);
    }
}

// Round 2
// 39.110 us; speedup vs baseline: 1.3678x; 1.3678x over previous
//
#include <hip/hip_runtime.h>

#define FS   5
#define NTAP 25
#define Bc   8
#define Cc   32
#define Hc   128
#define Wc   128
#define HW   (Hc * Wc)

// ---- apply-kernel tiling ----
#define TH     8            // rows per tile
#define TW     64           // cols per tile
#define Gc     8            // channels per block (looped)
#define HALO_H (TH + 4)     // 12
#define HALO_W (TW + 4)     // 68
#define HALO_N (HALO_H * HALO_W)   // 816

// ---------------- Kernel 1: per-pixel filter generation ----------------
// filt[b][t][h][w] = sum_c wg[t][c] * x[b][c][h][w] + bg[t]
__global__ __launch_bounds__(256, 4) void gen_filters_kernel(
    const float* __restrict__ x, const float* __restrict__ wg,
    const float* __restrict__ bg, float* __restrict__ filt)
{
    const int p = blockIdx.x * 256 + threadIdx.x;   // pixel index within image
    const int b = blockIdx.y;

    const float* xb = x + (size_t)b * Cc * HW + p;
    float xv[Cc];
#pragma unroll
    for (int c = 0; c < Cc; ++c) xv[c] = xb[(size_t)c * HW];

    float f[NTAP];
#pragma unroll
    for (int t = 0; t < NTAP; ++t) f[t] = bg[t];

#pragma unroll
    for (int t = 0; t < NTAP; ++t) {
#pragma unroll
        for (int c = 0; c < Cc; ++c) {
            f[t] = fmaf(wg[t * Cc + c], xv[c], f[t]);
        }
    }

    float* fb = filt + (size_t)b * NTAP * HW + p;
#pragma unroll
    for (int t = 0; t < NTAP; ++t) fb[(size_t)t * HW] = f[t];
}

// ---------------- Kernel 2: apply dynamic filters (5x5 stencil) ----------------
// 2 outputs/thread (float2), filters in 50 VGPRs, double-buffered LDS halo
// tiles with T14 async-stage split: issue next channel's global loads into
// regs -> compute current channel -> ds_write next buffer -> one barrier.
__global__ __launch_bounds__(256, 4) void apply_filters2_kernel(
    const float* __restrict__ x, const float* __restrict__ filt,
    float* __restrict__ out)
{
    __shared__ float xs[2][HALO_N];

    const int tid = threadIdx.x;        // 0..255
    const int tx  = tid & 31;           // 32 float2 columns
    const int ty  = tid >> 5;           // 8 rows
    const int ht  = blockIdx.x & 15;    // h tile 0..15
    const int wt  = blockIdx.x >> 4;    // w tile 0..1
    const int cg  = blockIdx.y;         // channel group 0..3
    const int b   = blockIdx.z;

    const int h0 = ht * TH;
    const int w0 = wt * TW;
    const int h  = h0 + ty;
    const int w2 = tx * 2;

    // ---- per-pixel filters for this thread's 2 pixels (coalesced plane loads) ----
    float2 f[NTAP];
    const float* fbp = filt + (size_t)b * NTAP * HW + (h * Wc + w0 + w2);
#pragma unroll
    for (int t = 0; t < NTAP; ++t)
        f[t] = *reinterpret_cast<const float2*>(fbp + (size_t)t * HW);

    const float* xb = x   + ((size_t)b * Cc + cg * Gc) * HW;
    float*       ob = out + ((size_t)b * Cc + cg * Gc) * HW;

    // ---- prologue: stage channel 0 into buffer 0 ----
    {
        const float* xc = xb;
#pragma unroll
        for (int k = 0; k < 4; ++k) {
            const int i = tid + k * 256;
            if (i < HALO_N) {
                const int r  = i / HALO_W;
                const int cw = i - r * HALO_W;
                const int gh = h0 - 2 + r;
                const int gw = w0 - 2 + cw;
                float v = 0.0f;
                if ((unsigned)gh < (unsigned)Hc && (unsigned)gw < (unsigned)Wc)
                    v = xc[gh * Wc + gw];
                xs[0][i] = v;
            }
        }
    }
    __syncthreads();

    for (int g = 0; g < Gc; ++g) {
        const int cur = g & 1;

        // T14 async-stage: issue next channel's global loads into registers
        float nv[4];
        if (g + 1 < Gc) {
            const float* xc = xb + (size_t)(g + 1) * HW;
#pragma unroll
            for (int k = 0; k < 4; ++k) {
                const int i = tid + k * 256;
                if (i < HALO_N) {
                    const int r  = i / HALO_W;
                    const int cw = i - r * HALO_W;
                    const int gh = h0 - 2 + r;
                    const int gw = w0 - 2 + cw;
                    float v = 0.0f;
                    if ((unsigned)gh < (unsigned)Hc && (unsigned)gw < (unsigned)Wc)
                        v = xc[gh * Wc + gw];
                    nv[k] = v;
                }
            }
        }

        // ---- 5x5 stencil from xs[cur] ----
        float2 acc = make_float2(0.0f, 0.0f);
#pragma unroll
        for (int di = 0; di < FS; ++di) {
            const float* row = &xs[cur][(ty + di) * HALO_W + w2];
            const float2 s01 = *reinterpret_cast<const float2*>(row);
            const float2 s23 = *reinterpret_cast<const float2*>(row + 2);
            const float2 s45 = *reinterpret_cast<const float2*>(row + 4);
            const float s[6] = { s01.x, s01.y, s23.x, s23.y, s45.x, s45.y };
#pragma unroll
            for (int dj = 0; dj < FS; ++dj) {
                const float2 ft = f[di * FS + dj];
                acc.x = fmaf(ft.x, s[dj],     acc.x);
                acc.y = fmaf(ft.y, s[dj + 1], acc.y);
            }
        }
        *reinterpret_cast<float2*>(ob + (size_t)g * HW + h * Wc + w0 + w2) = acc;

        // write next buffer (readers of it finished at end of previous iter)
        if (g + 1 < Gc) {
#pragma unroll
            for (int k = 0; k < 4; ++k) {
                const int i = tid + k * 256;
                if (i < HALO_N) xs[cur ^ 1][i] = nv[k];
            }
        }
        __syncthreads();
    }
}

// ---------------- Fallback: fused kernel (no workspace) ----------------
__global__ __launch_bounds__(256, 2) void fused_kernel(
    const float* __restrict__ x, const float* __restrict__ wg,
    const float* __restrict__ bg, float* __restrict__ out)
{
    __shared__ float xs[HALO_H][Wc + 4];

    const int tx = threadIdx.x;        // 0..31
    const int ty = threadIdx.y;        // 0..7
    const int h0 = blockIdx.x * TH;
    const int cg = blockIdx.y;
    const int b  = blockIdx.z;
    const int h  = h0 + ty;
    const int w4 = tx * 4;

    float4 f[NTAP];
#pragma unroll
    for (int t = 0; t < NTAP; ++t) {
        const float bv = bg[t];
        f[t] = make_float4(bv, bv, bv, bv);
    }
    const float* xpix = x + (size_t)b * Cc * HW + h * Wc + w4;
#pragma unroll
    for (int c = 0; c < Cc; ++c) {
        const float4 xv = *reinterpret_cast<const float4*>(xpix + (size_t)c * HW);
#pragma unroll
        for (int t = 0; t < NTAP; ++t) {
            const float wv = wg[t * Cc + c];
            f[t].x = fmaf(wv, xv.x, f[t].x);
            f[t].y = fmaf(wv, xv.y, f[t].y);
            f[t].z = fmaf(wv, xv.z, f[t].z);
            f[t].w = fmaf(wv, xv.w, f[t].w);
        }
    }

    const int tid = ty * 32 + tx;
    const float* xb = x   + ((size_t)b * Cc + cg * 8) * HW;
    float*       ob = out + ((size_t)b * Cc + cg * 8) * HW;

    for (int g = 0; g < 8; ++g) {
        __syncthreads();
        const float* xc = xb + (size_t)g * HW;
        for (int i = tid; i < HALO_H * (Wc + 4); i += 256) {
            const int r  = i / (Wc + 4);
            const int cw = i - r * (Wc + 4);
            const int gh = h0 - 2 + r;
            const int gw = cw - 2;
            float v = 0.0f;
            if ((unsigned)gh < (unsigned)Hc && (unsigned)gw < (unsigned)Wc)
                v = xc[gh * Wc + gw];
            xs[r][cw] = v;
        }
        __syncthreads();

        float4 acc = make_float4(0.f, 0.f, 0.f, 0.f);
#pragma unroll
        for (int di = 0; di < FS; ++di) {
            float w8[8];
#pragma unroll
            for (int k = 0; k < 8; ++k) w8[k] = xs[ty + di][w4 + k];
#pragma unroll
            for (int dj = 0; dj < FS; ++dj) {
                const float4 ft = f[di * FS + dj];
                acc.x = fmaf(ft.x, w8[0 + dj], acc.x);
                acc.y = fmaf(ft.y, w8[1 + dj], acc.y);
                acc.z = fmaf(ft.z, w8[2 + dj], acc.z);
                acc.w = fmaf(ft.w, w8[3 + dj], acc.w);
            }
        }
        *reinterpret_cast<float4*>(ob + (size_t)g * HW + h * Wc + w4) = acc;
    }
}

extern "C" void kernel_launch(void* const* d_in, const int* in_sizes, int n_in,
                              void* d_out, int out_size, void* d_ws, size_t ws_size,
                              hipStream_t stream) {
    const float* x  = (const float*)d_in[0];
    const float* wg = (const float*)d_in[1];
    const float* bg = (const float*)d_in[2];
    float* out = (float*)d_out;

    const size_t filt_bytes = (size_t)Bc * NTAP * HW * sizeof(float);

    if (ws_size >= filt_bytes) {
        float* filt = (float*)d_ws;
        gen_filters_kernel<<<dim3(HW / 256, Bc), 256, 0, stream>>>(x, wg, bg, filt);
        // grid.x = 16 h-tiles * 2 w-tiles (htile in low bits -> filt-sharing
        // blocks land on the same XCD under linear%8 round-robin)
        apply_filters2_kernel<<<dim3(32, Cc / Gc, Bc), 256, 0, stream>>>(x, filt, out);
    } else {
        fused_kernel<<<dim3(Hc / TH, Cc / 8, Bc), dim3(32, 8), 0, stream>>>(x, wg, bg, out);
    }
}

// Round 3
// 28.054 us; speedup vs baseline: 1.9069x; 1.3941x over previous
//
#include <hip/hip_runtime.h>

#define FS   5
#define NTAP 25
#define Bc   8
#define Cc   32
#define Hc   128
#define Wc   128
#define HW   (Hc * Wc)

// spatial tile per block
#define TH      8
#define TW      64
#define HALO_H  (TH + 4)              // 12
#define HALO_W  (TW + 4)              // 68
#define PLANE   (HALO_H * HALO_W)     // 816 floats per channel
#define NPAIR   (PLANE / 2)           // 408 float2 per channel
#define LDS_BYTES (Cc * PLANE * 4)    // 104448 B dynamic LDS

// One block = one 8x64 output tile of one batch image, all 32 channels.
// Phase 1: stage 32 halo planes (12x68) into LDS (float2, pair-uniform validity).
// Phase 2: per-thread filter gen (2 px, 25 taps) from LDS + uniform wg s_loads.
// Phase 3: per-channel 5x5 apply from LDS, float2 stores. One barrier total.
__global__ __launch_bounds__(256, 1) void ppdfn_fused_kernel(
    const float* __restrict__ x, const float* __restrict__ wg,
    const float* __restrict__ bg, float* __restrict__ out)
{
    extern __shared__ float xs[];     // [Cc][PLANE]

    const int tid = threadIdx.x;      // 0..255
    const int ht  = blockIdx.x;       // 0..15
    const int wt  = blockIdx.y;       // 0..1
    const int b   = blockIdx.z;       // 0..7
    const int h0  = ht * TH;
    const int w0  = wt * TW;

    // ---- staging address precompute (channel-independent, no div in loop) ----
    // pair index ip covers 2 consecutive floats of a plane; HALO_W is even and
    // w0-2+cw is even for even cw, so validity is uniform within each pair.
    int  goff[2];
    bool val[2];
    bool st1;
#pragma unroll
    for (int k = 0; k < 2; ++k) {
        const int ip = tid + k * 256;
        const int i  = ip * 2;
        const int r  = i / HALO_W;
        const int cw = i - r * HALO_W;
        const int gh = h0 - 2 + r;
        const int gw = w0 - 2 + cw;
        val[k]  = (ip < NPAIR) && ((unsigned)gh < (unsigned)Hc) &&
                  ((unsigned)gw < (unsigned)Wc);
        goff[k] = gh * Wc + gw;
    }
    st1 = (tid < NPAIR - 256);        // second pair slot exists

    const float* xb = x + (size_t)b * Cc * HW;

    // ---- phase 1: stage all channels ----
    for (int c = 0; c < Cc; ++c) {
        const float* xc = xb + (size_t)c * HW;
        float2 v0 = make_float2(0.f, 0.f), v1 = make_float2(0.f, 0.f);
        if (val[0]) v0 = *reinterpret_cast<const float2*>(xc + goff[0]);
        if (val[1]) v1 = *reinterpret_cast<const float2*>(xc + goff[1]);
        float* p = xs + c * PLANE;
        *reinterpret_cast<float2*>(p + 2 * tid) = v0;
        if (st1) *reinterpret_cast<float2*>(p + 2 * (tid + 256)) = v1;
    }
    __syncthreads();

    // ---- phase 2: per-pixel filter generation (2 px per thread) ----
    const int ty = tid >> 5;          // 0..7
    const int tx = tid & 31;          // 0..31
    const int w2 = tx * 2;

    float2 f[NTAP];
#pragma unroll
    for (int t = 0; t < NTAP; ++t) {
        const float bv = bg[t];
        f[t].x = bv; f[t].y = bv;
    }
#pragma unroll 2
    for (int c = 0; c < Cc; ++c) {
        const float2 xv = *reinterpret_cast<const float2*>(
            xs + c * PLANE + (ty + 2) * HALO_W + (w2 + 2));
#pragma unroll
        for (int t = 0; t < NTAP; ++t) {
            const float wv = wg[t * Cc + c];   // wave-uniform -> s_load
            f[t].x = fmaf(wv, xv.x, f[t].x);
            f[t].y = fmaf(wv, xv.y, f[t].y);
        }
    }

    // ---- phase 3: apply 5x5 dynamic filter per channel ----
    float* ob = out + (size_t)b * Cc * HW + (h0 + ty) * Wc + (w0 + w2);
#pragma unroll 2
    for (int c = 0; c < Cc; ++c) {
        const float* p = xs + c * PLANE + ty * HALO_W + w2;
        float accx = 0.f, accy = 0.f;
#pragma unroll
        for (int di = 0; di < FS; ++di) {
            const float* row = p + di * HALO_W;
            const float2 s01 = *reinterpret_cast<const float2*>(row);
            const float2 s23 = *reinterpret_cast<const float2*>(row + 2);
            const float2 s45 = *reinterpret_cast<const float2*>(row + 4);
            const float s0 = s01.x, s1 = s01.y, s2 = s23.x,
                        s3 = s23.y, s4 = s45.x, s5 = s45.y;
            const float2 f0 = f[di * FS + 0];
            const float2 f1 = f[di * FS + 1];
            const float2 f2 = f[di * FS + 2];
            const float2 f3 = f[di * FS + 3];
            const float2 f4 = f[di * FS + 4];
            accx = fmaf(f0.x, s0, accx);  accy = fmaf(f0.y, s1, accy);
            accx = fmaf(f1.x, s1, accx);  accy = fmaf(f1.y, s2, accy);
            accx = fmaf(f2.x, s2, accx);  accy = fmaf(f2.y, s3, accy);
            accx = fmaf(f3.x, s3, accx);  accy = fmaf(f3.y, s4, accy);
            accx = fmaf(f4.x, s4, accx);  accy = fmaf(f4.y, s5, accy);
        }
        *reinterpret_cast<float2*>(ob + (size_t)c * HW) = make_float2(accx, accy);
    }
}

extern "C" void kernel_launch(void* const* d_in, const int* in_sizes, int n_in,
                              void* d_out, int out_size, void* d_ws, size_t ws_size,
                              hipStream_t stream) {
    const float* x  = (const float*)d_in[0];
    const float* wg = (const float*)d_in[1];
    const float* bg = (const float*)d_in[2];
    float* out = (float*)d_out;

    ppdfn_fused_kernel<<<dim3(Hc / TH, Wc / TW, Bc), 256, LDS_BYTES, stream>>>(
        x, wg, bg, out);
}

// Round 4
// 24.073 us; speedup vs baseline: 2.2223x; 1.1654x over previous
//
#include <hip/hip_runtime.h>

#define FS   5
#define NTAP 25
#define Bc   8
#define Cc   32
#define Hc   128
#define Wc   128
#define HW   (Hc * Wc)

// spatial tile per block: 8 x 32, one pixel per thread (256 threads)
#define TH      8
#define TW      32
#define HALO_H  (TH + 4)              // 12
#define HALO_W  (TW + 4)              // 36
#define PLANE   (HALO_H * HALO_W)     // 432 floats per channel
#define NPAIR   (PLANE / 2)           // 216 float2 per channel
#define LDS_BYTES (Cc * PLANE * 4)    // 55296 B -> 2 blocks/CU

// One block = one 8x32 output tile of one batch image, all 32 channels in LDS.
// Phase 1: stage 32 halo planes, batched 8 channels/group (8 loads in flight).
// Phase 2: per-thread filter gen (1 px, 25 taps) from LDS, wg via s_loads.
// Phase 3: per-channel 5x5 apply from LDS. One barrier total.
__global__ __launch_bounds__(256, 2) void ppdfn_fused_kernel(
    const float* __restrict__ x, const float* __restrict__ wg,
    const float* __restrict__ bg, float* __restrict__ out)
{
    extern __shared__ float xs[];     // [Cc][PLANE]

    const int tid = threadIdx.x;      // 0..255
    const int ht  = blockIdx.x;       // 0..15
    const int wt  = blockIdx.y;       // 0..3
    const int b   = blockIdx.z;       // 0..7
    const int h0  = ht * TH;
    const int w0  = wt * TW;

    // ---- staging addresses (pair-uniform validity: HALO_W even, gw even) ----
    const int i  = tid * 2;           // float index within plane
    const int r  = tid / 18;          // i / HALO_W  (HALO_W = 36)
    const int cw = i - r * HALO_W;
    const int gh = h0 - 2 + r;
    const int gw = w0 - 2 + cw;
    const bool val = (tid < NPAIR) && ((unsigned)gh < (unsigned)Hc) &&
                     ((unsigned)gw < (unsigned)Wc);
    const bool stv = (tid < NPAIR);
    const int  go  = gh * Wc + gw;

    const float* xb = x + (size_t)b * Cc * HW;

    // ---- phase 1: stage all 32 channels, 8-channel batches ----
#pragma unroll
    for (int cg = 0; cg < Cc / 8; ++cg) {
        float2 rv[8];
#pragma unroll
        for (int u = 0; u < 8; ++u) {
            float2 v = make_float2(0.f, 0.f);
            if (val)
                v = *reinterpret_cast<const float2*>(
                        xb + (size_t)(cg * 8 + u) * HW + go);
            rv[u] = v;
        }
#pragma unroll
        for (int u = 0; u < 8; ++u) {
            if (stv)
                *reinterpret_cast<float2*>(xs + (cg * 8 + u) * PLANE + i) = rv[u];
        }
    }
    __syncthreads();

    // ---- phase 2: per-pixel filter generation (1 px per thread) ----
    const int ty = tid >> 5;          // 0..7
    const int tx = tid & 31;          // 0..31

    float f[NTAP];
#pragma unroll
    for (int t = 0; t < NTAP; ++t) f[t] = bg[t];

#pragma unroll 4
    for (int c = 0; c < Cc; ++c) {
        const float xv = xs[c * PLANE + (ty + 2) * HALO_W + (tx + 2)];
#pragma unroll
        for (int t = 0; t < NTAP; ++t)
            f[t] = fmaf(wg[t * Cc + c], xv, f[t]);   // wg uniform -> s_load
    }

    // ---- phase 3: apply 5x5 dynamic filter per channel ----
    float* ob = out + (size_t)b * Cc * HW + (h0 + ty) * Wc + (w0 + tx);
#pragma unroll 2
    for (int c = 0; c < Cc; ++c) {
        const float* p = xs + c * PLANE + ty * HALO_W + tx;
        float acc = 0.f;
#pragma unroll
        for (int di = 0; di < FS; ++di) {
            const float* row = p + di * HALO_W;
            const float s0 = row[0];
            const float s1 = row[1];
            const float s2 = row[2];
            const float s3 = row[3];
            const float s4 = row[4];
            acc = fmaf(f[di * FS + 0], s0, acc);
            acc = fmaf(f[di * FS + 1], s1, acc);
            acc = fmaf(f[di * FS + 2], s2, acc);
            acc = fmaf(f[di * FS + 3], s3, acc);
            acc = fmaf(f[di * FS + 4], s4, acc);
        }
        ob[(size_t)c * HW] = acc;
    }
}

extern "C" void kernel_launch(void* const* d_in, const int* in_sizes, int n_in,
                              void* d_out, int out_size, void* d_ws, size_t ws_size,
                              hipStream_t stream) {
    const float* x  = (const float*)d_in[0];
    const float* wg = (const float*)d_in[1];
    const float* bg = (const float*)d_in[2];
    float* out = (float*)d_out;

    ppdfn_fused_kernel<<<dim3(Hc / TH, Wc / TW, Bc), 256, LDS_BYTES, stream>>>(
        x, wg, bg, out);
}